// Round 4
// baseline (616.081 us; speedup 1.0000x reference)
//
#include <hip/hip_runtime.h>

#define NODES 50000
#define MP    50048          // NODES padded to multiple of 128
#define EDGES 800000
#define GRAPHS 500
#define DIN 128
#define HID 512

typedef short bf16x8 __attribute__((ext_vector_type(8)));
typedef float f32x4 __attribute__((ext_vector_type(4)));

__device__ inline float bf2f(unsigned short u) { return __uint_as_float(((unsigned)u) << 16); }
__device__ inline unsigned short f2b(float f) {
    unsigned u = __float_as_uint(f);
    return (unsigned short)((u + 0x7fffu + ((u >> 16) & 1u)) >> 16);  // RNE
}
__device__ inline float bl(unsigned u) { return __uint_as_float(u << 16); }
__device__ inline float bh(unsigned u) { return __uint_as_float(u & 0xffff0000u); }

// ---------------- graph structure build ----------------

__global__ void count_deg(const int* __restrict__ row, int* __restrict__ deg, int E) {
    int e = blockIdx.x * 256 + threadIdx.x;
    if (e < E) atomicAdd(&deg[row[e]], 1);
}

__global__ void compute_dinv(const int* __restrict__ deg, float* __restrict__ dinv, int N) {
    int n = blockIdx.x * 256 + threadIdx.x;
    if (n < N) dinv[n] = rsqrtf((float)(deg[n] + 1));  // +1 self loop
}

__global__ __launch_bounds__(1024) void scan_offsets(const int* __restrict__ deg,
                                                     int* __restrict__ off, int N) {
    __shared__ int sums[1024];
    int tid = threadIdx.x;
    int chunk = (N + 1023) / 1024;
    int start = tid * chunk;
    int end = min(start + chunk, N);
    int s = 0;
    for (int i = start; i < end; ++i) s += deg[i];
    sums[tid] = s;
    __syncthreads();
    for (int o = 1; o < 1024; o <<= 1) {
        int v = (tid >= o) ? sums[tid - o] : 0;
        __syncthreads();
        sums[tid] += v;
        __syncthreads();
    }
    int run = sums[tid] - s;  // exclusive prefix
    for (int i = start; i < end; ++i) { off[i] = run; run += deg[i]; }
    if (tid == 1023) off[N] = sums[1023];
}

__global__ void fill_csr(const int* __restrict__ row, const int* __restrict__ col,
                         const int* __restrict__ off, int* __restrict__ cursor,
                         int* __restrict__ csr_col, int E) {
    int e = blockIdx.x * 256 + threadIdx.x;
    if (e < E) {
        int r = row[e];
        int p = atomicAdd(&cursor[r], 1);
        csr_col[off[r] + p] = col[e];
    }
}

// ---------------- graph pooling structure ----------------

__global__ void count_graph(const int* __restrict__ ngi, int* __restrict__ gcnt, int N) {
    int n = blockIdx.x * 256 + threadIdx.x;
    if (n < N) atomicAdd(&gcnt[ngi[n]], 1);
}

__global__ __launch_bounds__(512) void scan_graph(const int* __restrict__ gcnt,
                                                  int* __restrict__ goff) {
    __shared__ int s[512];
    int t = threadIdx.x;
    s[t] = (t < GRAPHS) ? gcnt[t] : 0;
    __syncthreads();
    for (int o = 1; o < 512; o <<= 1) {
        int v = (t >= o) ? s[t - o] : 0;
        __syncthreads();
        s[t] += v;
        __syncthreads();
    }
    if (t == 0) goff[0] = 0;
    if (t < GRAPHS) goff[t + 1] = s[t];
}

// ---------------- conversions ----------------

__global__ void cvt_x_bf16(const float* __restrict__ x, unsigned short* __restrict__ xb, int n4) {
    int i = blockIdx.x * 256 + threadIdx.x;
    if (i < n4) {
        float4 v = ((const float4*)x)[i];
        ushort4 o;
        o.x = f2b(v.x); o.y = f2b(v.y); o.z = f2b(v.z); o.w = f2b(v.w);
        ((ushort4*)xb)[i] = o;
    }
}

// W[K][512] -> WT[512][K] bf16
template <int K>
__global__ void transpose_w(const float* __restrict__ W, unsigned short* __restrict__ WT) {
    int n = blockIdx.x * 256 + threadIdx.x;  // column
    int k = blockIdx.y;
    if (n < HID) WT[(size_t)n * K + k] = f2b(W[(size_t)k * HID + n]);
}

// ---------------- feature-sliced GCN aggregation with XCD affinity ----------------
// D features split into NSL slices of 64; slice = blockIdx % NSL so (with the
// round-robin block->XCD heuristic) each XCD's L2 only holds a 6.4 MB slice.
// Block = 4 waves = 4 nodes, one slice. Lane = 1 feature (ushort).
// out[n,f] = EPI ? relu(dn*(sum) + bias[f]) : dn*(sum)

template <int D, int NSL, bool EPI>
__global__ __launch_bounds__(256) void agg_sliced(const unsigned short* __restrict__ H,
                                                  const int* __restrict__ off,
                                                  const int* __restrict__ csr_col,
                                                  const float* __restrict__ dinv,
                                                  const float* __restrict__ bias,
                                                  unsigned short* __restrict__ out) {
    const int bid = blockIdx.x;
    const int slice = bid & (NSL - 1);
    const int chunk = bid / NSL;
    const int n = chunk * 4 + (threadIdx.x >> 6);
    if (n >= NODES) return;
    const int l = threadIdx.x & 63;
    const int f = slice * 64 + l;
    const float dn = dinv[n];
    float a = bf2f(H[(size_t)n * D + f]) * dn;   // self loop
    const int s = off[n], e = off[n + 1];
    int i = s;
    for (; i + 4 <= e; i += 4) {
        int c0 = csr_col[i], c1 = csr_col[i + 1], c2 = csr_col[i + 2], c3 = csr_col[i + 3];
        float d0 = dinv[c0], d1 = dinv[c1], d2 = dinv[c2], d3 = dinv[c3];
        float v0 = bf2f(H[(size_t)c0 * D + f]);
        float v1 = bf2f(H[(size_t)c1 * D + f]);
        float v2 = bf2f(H[(size_t)c2 * D + f]);
        float v3 = bf2f(H[(size_t)c3 * D + f]);
        a += v0 * d0; a += v1 * d1; a += v2 * d2; a += v3 * d3;
    }
    for (; i < e; ++i) {
        int c = csr_col[i];
        a += bf2f(H[(size_t)c * D + f]) * dinv[c];
    }
    a *= dn;
    if (EPI) a = fmaxf(a + bias[f], 0.f);
    out[(size_t)n * D + f] = f2b(a);
}

// ---------------- bf16 MFMA GEMM: C[MP][512] = A[MP][K] @ W[K][512] ----------------
// 128x128 tile, BK=64, 4 waves; global_load_lds(16B) staging with XOR chunk
// swizzle. 1D grid + bijective XCD chunk-swizzle (N fastest within a chunk) so
// each XCD covers a contiguous M range -> A-panel fetched once per chip/8.

template <int K, bool EPI>
__global__ __launch_bounds__(256) void gemm_mfma(const unsigned short* __restrict__ A,
                                                 const unsigned short* __restrict__ BT,
                                                 const float* __restrict__ bias,
                                                 unsigned short* __restrict__ C) {
    __shared__ unsigned short As[128 * 64];
    __shared__ unsigned short Bs[128 * 64];
    // bijective XCD swizzle (m204): xcd x gets a contiguous swz chunk
    const int nwg = gridDim.x;
    const int q = nwg >> 3, r = nwg & 7;
    const int x = blockIdx.x & 7, ii = blockIdx.x >> 3;
    const int swz = (x < r ? x * (q + 1) : r * (q + 1) + (x - r) * q) + ii;
    const int m0 = (swz >> 2) * 128;   // 4 N-tiles, fastest
    const int n0 = (swz & 3) * 128;

    const int t = threadIdx.x;
    const int w = t >> 6, l = t & 63;
    const int wr = w >> 1, wc = w & 1;
    f32x4 acc[4][4] = {};
    const int lr = l >> 3;                 // row within 8-row group
    const int swzc = (l & 7) ^ lr;         // pre-swizzled source chunk

    for (int k0 = 0; k0 < K; k0 += 64) {
#pragma unroll
        for (int c = 0; c < 4; ++c) {
            const int rg = (w * 4 + c) * 8;  // tile-local row-group base
            const unsigned short* ga = &A[(size_t)(m0 + rg + lr) * K + k0 + swzc * 8];
            const unsigned short* gb = &BT[(size_t)(n0 + rg + lr) * K + k0 + swzc * 8];
            __builtin_amdgcn_global_load_lds(
                (const __attribute__((address_space(1))) void*)ga,
                (__attribute__((address_space(3))) void*)&As[rg * 64], 16, 0, 0);
            __builtin_amdgcn_global_load_lds(
                (const __attribute__((address_space(1))) void*)gb,
                (__attribute__((address_space(3))) void*)&Bs[rg * 64], 16, 0, 0);
        }
        __syncthreads();
#pragma unroll
        for (int kk = 0; kk < 2; ++kk) {
            const int ch = (kk * 4 + (l >> 4)) ^ (l & 7);  // swizzled read chunk
            bf16x8 af[4], bg[4];
#pragma unroll
            for (int m = 0; m < 4; ++m)
                af[m] = *(const bf16x8*)&As[(wr * 64 + m * 16 + (l & 15)) * 64 + ch * 8];
#pragma unroll
            for (int n = 0; n < 4; ++n)
                bg[n] = *(const bf16x8*)&Bs[(wc * 64 + n * 16 + (l & 15)) * 64 + ch * 8];
#pragma unroll
            for (int m = 0; m < 4; ++m)
#pragma unroll
                for (int n = 0; n < 4; ++n)
                    acc[m][n] = __builtin_amdgcn_mfma_f32_16x16x32_bf16(af[m], bg[n], acc[m][n], 0, 0, 0);
        }
        __syncthreads();
    }
    const int ro = 4 * (l >> 4);
    const int co = l & 15;
#pragma unroll
    for (int m = 0; m < 4; ++m)
#pragma unroll
        for (int n = 0; n < 4; ++n) {
            int col = n0 + wc * 64 + n * 16 + co;
            float bv = EPI ? bias[col] : 0.f;
#pragma unroll
            for (int r = 0; r < 4; ++r) {
                int row = m0 + wr * 64 + m * 16 + ro + r;
                float v = acc[m][n][r];
                if (EPI) v = fmaxf(v + bv, 0.f);
                C[(size_t)row * HID + col] = f2b(v);
            }
        }
}

// ---------------- sum pooling per graph (sorted ngi -> ranges) ----------------

__global__ __launch_bounds__(64) void pool_bf16(const unsigned short* __restrict__ H,
                                                const int* __restrict__ goff,
                                                float* __restrict__ gh) {
    int g = blockIdx.x, l = threadIdx.x;
    int s = goff[g], e = goff[g + 1];
    float a0 = 0, a1 = 0, a2 = 0, a3 = 0, a4 = 0, a5 = 0, a6 = 0, a7 = 0;
    for (int n = s; n < e; ++n) {
        uint4 v = ((const uint4*)H)[(size_t)n * 64 + l];
        a0 += bl(v.x); a1 += bh(v.x); a2 += bl(v.y); a3 += bh(v.y);
        a4 += bl(v.z); a5 += bh(v.z); a6 += bl(v.w); a7 += bh(v.w);
    }
    float4* o = (float4*)(gh + (size_t)g * HID);
    o[l * 2]     = make_float4(a0, a1, a2, a3);
    o[l * 2 + 1] = make_float4(a4, a5, a6, a7);
}

// ---------------- classifier ----------------

__global__ __launch_bounds__(64) void logits_kernel(const float* __restrict__ gh,
                                                    const float* __restrict__ Wfc,
                                                    const float* __restrict__ bfc,
                                                    float* __restrict__ out) {
    int g = blockIdx.x;
    int t = threadIdx.x;
    float p0 = 0.f, p1 = 0.f;
    for (int k = t; k < HID; k += 64) {
        float h = gh[(size_t)g * HID + k];
        p0 += h * Wfc[k * 2 + 0];
        p1 += h * Wfc[k * 2 + 1];
    }
#pragma unroll
    for (int o = 32; o > 0; o >>= 1) {
        p0 += __shfl_down(p0, o);
        p1 += __shfl_down(p1, o);
    }
    if (t == 0) {
        out[g * 2 + 0] = p0 + bfc[0];
        out[g * 2 + 1] = p1 + bfc[1];
    }
}

// ---------------- launch ----------------

extern "C" void kernel_launch(void* const* d_in, const int* in_sizes, int n_in,
                              void* d_out, int out_size, void* d_ws, size_t ws_size,
                              hipStream_t stream) {
    const float* x   = (const float*)d_in[0];
    const int*   ei  = (const int*)d_in[1];
    const int*   ngi = (const int*)d_in[2];
    const float* W0  = (const float*)d_in[3];
    const float* b0  = (const float*)d_in[4];
    const float* W1  = (const float*)d_in[5];
    const float* b1  = (const float*)d_in[6];
    const float* Wfc = (const float*)d_in[7];
    const float* bfc = (const float*)d_in[8];
    float* out = (float*)d_out;

    const int* row = ei;
    const int* col = ei + EDGES;

    char* ws = (char*)d_ws;
    size_t o = 0;
    auto alloc = [&](size_t bytes) {
        o = (o + 255) & ~(size_t)255;
        void* p = ws + o;
        o += bytes;
        return p;
    };
    unsigned short* XB  = (unsigned short*)alloc((size_t)NODES * DIN * 2);  // bf16 x
    unsigned short* XA  = (unsigned short*)alloc((size_t)MP * DIN * 2);     // agg(x)
    unsigned short* H   = (unsigned short*)alloc((size_t)MP * HID * 2);     // relu(XA@W0+b0), reused for h2
    unsigned short* G   = (unsigned short*)alloc((size_t)MP * HID * 2);     // H@W1
    unsigned short* W0T = (unsigned short*)alloc((size_t)HID * DIN * 2);
    unsigned short* W1T = (unsigned short*)alloc((size_t)HID * HID * 2);
    float* gh    = (float*)alloc((size_t)GRAPHS * HID * 4);
    int*   deg   = (int*)alloc((size_t)NODES * 4);
    float* dinv  = (float*)alloc((size_t)NODES * 4);
    int*   off   = (int*)alloc((size_t)(NODES + 1) * 4);
    int*   cursor= (int*)alloc((size_t)NODES * 4);
    int*   csr   = (int*)alloc((size_t)EDGES * 4);
    int*   gcnt  = (int*)alloc(512 * 4);
    int*   goff  = (int*)alloc(512 * 4);

    hipMemsetAsync(deg, 0, (size_t)NODES * 4, stream);
    hipMemsetAsync(cursor, 0, (size_t)NODES * 4, stream);
    hipMemsetAsync(gcnt, 0, 512 * 4, stream);
    // pad rows of XA must be finite (GEMM0 reads all MP rows)
    hipMemsetAsync(XA + (size_t)NODES * DIN, 0, (size_t)(MP - NODES) * DIN * 2, stream);

    count_deg<<<(EDGES + 255) / 256, 256, 0, stream>>>(row, deg, EDGES);
    compute_dinv<<<(NODES + 255) / 256, 256, 0, stream>>>(deg, dinv, NODES);
    scan_offsets<<<1, 1024, 0, stream>>>(deg, off, NODES);
    fill_csr<<<(EDGES + 255) / 256, 256, 0, stream>>>(row, col, off, cursor, csr, EDGES);
    count_graph<<<(NODES + 255) / 256, 256, 0, stream>>>(ngi, gcnt, NODES);
    scan_graph<<<1, 512, 0, stream>>>(gcnt, goff);

    cvt_x_bf16<<<((NODES * DIN / 4) + 255) / 256, 256, 0, stream>>>(x, XB, NODES * DIN / 4);
    transpose_w<DIN><<<dim3(2, DIN), 256, 0, stream>>>(W0, W0T);
    transpose_w<HID><<<dim3(2, HID), 256, 0, stream>>>(W1, W1T);

    const int chunks = (NODES + 3) / 4;
    // layer 0 (reordered): XA = agg(XB) [2 slices]; H = relu(XA @ W0 + b0)
    agg_sliced<DIN, 2, false><<<chunks * 2, 256, 0, stream>>>(XB, off, csr, dinv, nullptr, XA);
    gemm_mfma<DIN, true><<<4 * (MP / 128), 256, 0, stream>>>(XA, W0T, b0, H);

    // layer 1: G = H @ W1 ; H = relu(agg(G) + b1) [8 slices]
    gemm_mfma<HID, false><<<4 * (MP / 128), 256, 0, stream>>>(H, W1T, nullptr, G);
    agg_sliced<HID, 8, true><<<chunks * 8, 256, 0, stream>>>(G, off, csr, dinv, b1, H);

    // pooling + classifier
    pool_bf16<<<GRAPHS, 64, 0, stream>>>(H, goff, gh);
    logits_kernel<<<GRAPHS, 64, 0, stream>>>(gh, Wfc, bfc, out);
}

// Round 5
// 485.341 us; speedup vs baseline: 1.2694x; 1.2694x over previous
//
#include <hip/hip_runtime.h>

#define NODES 50000
#define MP    50048          // NODES padded to multiple of 128
#define EDGES 800000
#define GRAPHS 500
#define DIN 128
#define HID 512

typedef short bf16x8 __attribute__((ext_vector_type(8)));
typedef float f32x4 __attribute__((ext_vector_type(4)));

__device__ inline float bl(unsigned u) { return __uint_as_float(u << 16); }
__device__ inline float bh(unsigned u) { return __uint_as_float(u & 0xffff0000u); }
__device__ inline unsigned short f2b(float f) {
    unsigned u = __float_as_uint(f);
    return (unsigned short)((u + 0x7fffu + ((u >> 16) & 1u)) >> 16);  // RNE
}

// ---------------- graph structure build ----------------

__global__ void count_deg(const int* __restrict__ row, int* __restrict__ deg, int E) {
    int e = blockIdx.x * 256 + threadIdx.x;
    if (e < E) atomicAdd(&deg[row[e]], 1);
}

__global__ void compute_dinv(const int* __restrict__ deg, float* __restrict__ dinv, int N) {
    int n = blockIdx.x * 256 + threadIdx.x;
    if (n < N) dinv[n] = rsqrtf((float)(deg[n] + 1));  // +1 self loop
}

__global__ __launch_bounds__(1024) void scan_offsets(const int* __restrict__ deg,
                                                     int* __restrict__ off, int N) {
    __shared__ int sums[1024];
    int tid = threadIdx.x;
    int chunk = (N + 1023) / 1024;
    int start = tid * chunk;
    int end = min(start + chunk, N);
    int s = 0;
    for (int i = start; i < end; ++i) s += deg[i];
    sums[tid] = s;
    __syncthreads();
    for (int o = 1; o < 1024; o <<= 1) {
        int v = (tid >= o) ? sums[tid - o] : 0;
        __syncthreads();
        sums[tid] += v;
        __syncthreads();
    }
    int run = sums[tid] - s;  // exclusive prefix
    for (int i = start; i < end; ++i) { off[i] = run; run += deg[i]; }
    if (tid == 1023) off[N] = sums[1023];
}

__global__ void fill_csr(const int* __restrict__ row, const int* __restrict__ col,
                         const int* __restrict__ off, int* __restrict__ cursor,
                         int* __restrict__ csr_col, int E) {
    int e = blockIdx.x * 256 + threadIdx.x;
    if (e < E) {
        int r = row[e];
        int p = atomicAdd(&cursor[r], 1);
        csr_col[off[r] + p] = col[e];
    }
}

// ---------------- graph pooling structure ----------------

__global__ void count_graph(const int* __restrict__ ngi, int* __restrict__ gcnt, int N) {
    int n = blockIdx.x * 256 + threadIdx.x;
    if (n < N) atomicAdd(&gcnt[ngi[n]], 1);
}

__global__ __launch_bounds__(512) void scan_graph(const int* __restrict__ gcnt,
                                                  int* __restrict__ goff) {
    __shared__ int s[512];
    int t = threadIdx.x;
    s[t] = (t < GRAPHS) ? gcnt[t] : 0;
    __syncthreads();
    for (int o = 1; o < 512; o <<= 1) {
        int v = (t >= o) ? s[t - o] : 0;
        __syncthreads();
        s[t] += v;
        __syncthreads();
    }
    if (t == 0) goff[0] = 0;
    if (t < GRAPHS) goff[t + 1] = s[t];
}

// ---------------- conversions ----------------

__global__ void cvt_x_bf16(const float* __restrict__ x, unsigned short* __restrict__ xb, int n4) {
    int i = blockIdx.x * 256 + threadIdx.x;
    if (i < n4) {
        float4 v = ((const float4*)x)[i];
        ushort4 o;
        o.x = f2b(v.x); o.y = f2b(v.y); o.z = f2b(v.z); o.w = f2b(v.w);
        ((ushort4*)xb)[i] = o;
    }
}

// W[K][512] -> WT[512][K] bf16
template <int K>
__global__ void transpose_w(const float* __restrict__ W, unsigned short* __restrict__ WT) {
    int n = blockIdx.x * 256 + threadIdx.x;  // column
    int k = blockIdx.y;
    if (n < HID) WT[(size_t)n * K + k] = f2b(W[(size_t)k * HID + n]);
}

// ---------------- 4-row-group gather aggregation ----------------
// Wave = 1 node; 64 lanes in 4 groups of 16; each group gathers a DIFFERENT
// neighbor's 128-feature slice as uint4 (16B/lane, 1KB/wave total) -> 4 edges
// per iteration at round-2 issue cost. Cross-group reduce via shfl_xor.

__device__ inline void acc8(float* a, uint4 v, float d) {
    a[0] += bl(v.x) * d; a[1] += bh(v.x) * d;
    a[2] += bl(v.y) * d; a[3] += bh(v.y) * d;
    a[4] += bl(v.z) * d; a[5] += bh(v.z) * d;
    a[6] += bl(v.w) * d; a[7] += bh(v.w) * d;
}

// D=512, NSL=4 feature slices (slice = bid&3 -> XCD affinity), fused bias+relu.
__global__ __launch_bounds__(256) void agg512_g4(const unsigned short* __restrict__ H,
                                                 const int* __restrict__ off,
                                                 const int* __restrict__ csr_col,
                                                 const float* __restrict__ dinv,
                                                 const float* __restrict__ bias,
                                                 unsigned short* __restrict__ out) {
    const int bid = blockIdx.x;
    const int slice = bid & 3;
    const int n = (bid >> 2) * 4 + (threadIdx.x >> 6);
    if (n >= NODES) return;
    const int l = threadIdx.x & 63;
    const int g = l >> 4, j = l & 15;
    const uint4* H4 = (const uint4*)H;          // 64 uint4 per row
    const int fo = slice * 16 + j;              // uint4 index within row
    const float dn = dinv[n];
    float a[8] = {};
    if (g == 0) acc8(a, H4[(size_t)n * 64 + fo], dn);   // self loop
    const int s = off[n], e = off[n + 1];
    for (int i = s; i < e; i += 4) {
        int idx = i + g;
        int c = csr_col[idx < e ? idx : s];
        float d = (idx < e) ? dinv[c] : 0.f;
        acc8(a, H4[(size_t)c * 64 + fo], d);
    }
#pragma unroll
    for (int k = 0; k < 8; ++k) a[k] += __shfl_xor(a[k], 16);
#pragma unroll
    for (int k = 0; k < 8; ++k) a[k] += __shfl_xor(a[k], 32);
    if (l < 16) {
        const int f = slice * 128 + j * 8;
        float4 b0 = ((const float4*)bias)[f >> 2];
        float4 b1 = ((const float4*)bias)[(f >> 2) + 1];
        float o0 = fmaxf(a[0] * dn + b0.x, 0.f), o1 = fmaxf(a[1] * dn + b0.y, 0.f);
        float o2 = fmaxf(a[2] * dn + b0.z, 0.f), o3 = fmaxf(a[3] * dn + b0.w, 0.f);
        float o4 = fmaxf(a[4] * dn + b1.x, 0.f), o5 = fmaxf(a[5] * dn + b1.y, 0.f);
        float o6 = fmaxf(a[6] * dn + b1.z, 0.f), o7 = fmaxf(a[7] * dn + b1.w, 0.f);
        uint4 ov;
        ov.x = (unsigned)f2b(o0) | ((unsigned)f2b(o1) << 16);
        ov.y = (unsigned)f2b(o2) | ((unsigned)f2b(o3) << 16);
        ov.z = (unsigned)f2b(o4) | ((unsigned)f2b(o5) << 16);
        ov.w = (unsigned)f2b(o6) | ((unsigned)f2b(o7) << 16);
        ((uint4*)out)[(size_t)n * 64 + fo] = ov;
    }
}

// D=128, no slicing (whole row per wave), 4 rows per iteration, output scaled
// by dn (no bias/relu) -> XA.
__global__ __launch_bounds__(256) void aggx_g4(const unsigned short* __restrict__ X,
                                               const int* __restrict__ off,
                                               const int* __restrict__ csr_col,
                                               const float* __restrict__ dinv,
                                               unsigned short* __restrict__ XA) {
    const int n = blockIdx.x * 4 + (threadIdx.x >> 6);
    if (n >= NODES) return;
    const int l = threadIdx.x & 63;
    const int g = l >> 4, j = l & 15;
    const uint4* X4 = (const uint4*)X;          // 16 uint4 per row
    const float dn = dinv[n];
    float a[8] = {};
    if (g == 0) acc8(a, X4[(size_t)n * 16 + j], dn);    // self loop
    const int s = off[n], e = off[n + 1];
    for (int i = s; i < e; i += 4) {
        int idx = i + g;
        int c = csr_col[idx < e ? idx : s];
        float d = (idx < e) ? dinv[c] : 0.f;
        acc8(a, X4[(size_t)c * 16 + j], d);
    }
#pragma unroll
    for (int k = 0; k < 8; ++k) a[k] += __shfl_xor(a[k], 16);
#pragma unroll
    for (int k = 0; k < 8; ++k) a[k] += __shfl_xor(a[k], 32);
    if (l < 16) {
        uint4 ov;
        ov.x = (unsigned)f2b(a[0] * dn) | ((unsigned)f2b(a[1] * dn) << 16);
        ov.y = (unsigned)f2b(a[2] * dn) | ((unsigned)f2b(a[3] * dn) << 16);
        ov.z = (unsigned)f2b(a[4] * dn) | ((unsigned)f2b(a[5] * dn) << 16);
        ov.w = (unsigned)f2b(a[6] * dn) | ((unsigned)f2b(a[7] * dn) << 16);
        ((uint4*)XA)[(size_t)n * 16 + j] = ov;
    }
}

// ---------------- bf16 MFMA GEMM: C[MP][512] = A[MP][K] @ W[K][512] ----------------
// 128x128 tile, BK=64, 4 waves; global_load_lds(16B) staging with XOR chunk
// swizzle. 1D grid + bijective XCD chunk-swizzle (N fastest within a chunk).

template <int K, bool EPI>
__global__ __launch_bounds__(256) void gemm_mfma(const unsigned short* __restrict__ A,
                                                 const unsigned short* __restrict__ BT,
                                                 const float* __restrict__ bias,
                                                 unsigned short* __restrict__ C) {
    __shared__ unsigned short As[128 * 64];
    __shared__ unsigned short Bs[128 * 64];
    const int nwg = gridDim.x;
    const int q = nwg >> 3, r = nwg & 7;
    const int x = blockIdx.x & 7, ii = blockIdx.x >> 3;
    const int swz = (x < r ? x * (q + 1) : r * (q + 1) + (x - r) * q) + ii;
    const int m0 = (swz >> 2) * 128;   // 4 N-tiles, fastest
    const int n0 = (swz & 3) * 128;

    const int t = threadIdx.x;
    const int w = t >> 6, l = t & 63;
    const int wr = w >> 1, wc = w & 1;
    f32x4 acc[4][4] = {};
    const int lr = l >> 3;                 // row within 8-row group
    const int swzc = (l & 7) ^ lr;         // pre-swizzled source chunk

    for (int k0 = 0; k0 < K; k0 += 64) {
#pragma unroll
        for (int c = 0; c < 4; ++c) {
            const int rg = (w * 4 + c) * 8;  // tile-local row-group base
            const unsigned short* ga = &A[(size_t)(m0 + rg + lr) * K + k0 + swzc * 8];
            const unsigned short* gb = &BT[(size_t)(n0 + rg + lr) * K + k0 + swzc * 8];
            __builtin_amdgcn_global_load_lds(
                (const __attribute__((address_space(1))) void*)ga,
                (__attribute__((address_space(3))) void*)&As[rg * 64], 16, 0, 0);
            __builtin_amdgcn_global_load_lds(
                (const __attribute__((address_space(1))) void*)gb,
                (__attribute__((address_space(3))) void*)&Bs[rg * 64], 16, 0, 0);
        }
        __syncthreads();
#pragma unroll
        for (int kk = 0; kk < 2; ++kk) {
            const int ch = (kk * 4 + (l >> 4)) ^ (l & 7);  // swizzled read chunk
            bf16x8 af[4], bg[4];
#pragma unroll
            for (int m = 0; m < 4; ++m)
                af[m] = *(const bf16x8*)&As[(wr * 64 + m * 16 + (l & 15)) * 64 + ch * 8];
#pragma unroll
            for (int n = 0; n < 4; ++n)
                bg[n] = *(const bf16x8*)&Bs[(wc * 64 + n * 16 + (l & 15)) * 64 + ch * 8];
#pragma unroll
            for (int m = 0; m < 4; ++m)
#pragma unroll
                for (int n = 0; n < 4; ++n)
                    acc[m][n] = __builtin_amdgcn_mfma_f32_16x16x32_bf16(af[m], bg[n], acc[m][n], 0, 0, 0);
        }
        __syncthreads();
    }
    const int ro = 4 * (l >> 4);
    const int co = l & 15;
#pragma unroll
    for (int m = 0; m < 4; ++m)
#pragma unroll
        for (int n = 0; n < 4; ++n) {
            int col = n0 + wc * 64 + n * 16 + co;
            float bv = EPI ? bias[col] : 0.f;
#pragma unroll
            for (int r = 0; r < 4; ++r) {
                int row = m0 + wr * 64 + m * 16 + ro + r;
                float v = acc[m][n][r];
                if (EPI) v = fmaxf(v + bv, 0.f);
                C[(size_t)row * HID + col] = f2b(v);
            }
        }
}

// ---------------- sum pooling per graph (sorted ngi -> ranges) ----------------

__global__ __launch_bounds__(64) void pool_bf16(const unsigned short* __restrict__ H,
                                                const int* __restrict__ goff,
                                                float* __restrict__ gh) {
    int g = blockIdx.x, l = threadIdx.x;
    int s = goff[g], e = goff[g + 1];
    float a0 = 0, a1 = 0, a2 = 0, a3 = 0, a4 = 0, a5 = 0, a6 = 0, a7 = 0;
    for (int n = s; n < e; ++n) {
        uint4 v = ((const uint4*)H)[(size_t)n * 64 + l];
        a0 += bl(v.x); a1 += bh(v.x); a2 += bl(v.y); a3 += bh(v.y);
        a4 += bl(v.z); a5 += bh(v.z); a6 += bl(v.w); a7 += bh(v.w);
    }
    float4* o = (float4*)(gh + (size_t)g * HID);
    o[l * 2]     = make_float4(a0, a1, a2, a3);
    o[l * 2 + 1] = make_float4(a4, a5, a6, a7);
}

// ---------------- classifier ----------------

__global__ __launch_bounds__(64) void logits_kernel(const float* __restrict__ gh,
                                                    const float* __restrict__ Wfc,
                                                    const float* __restrict__ bfc,
                                                    float* __restrict__ out) {
    int g = blockIdx.x;
    int t = threadIdx.x;
    float p0 = 0.f, p1 = 0.f;
    for (int k = t; k < HID; k += 64) {
        float h = gh[(size_t)g * HID + k];
        p0 += h * Wfc[k * 2 + 0];
        p1 += h * Wfc[k * 2 + 1];
    }
#pragma unroll
    for (int o = 32; o > 0; o >>= 1) {
        p0 += __shfl_down(p0, o);
        p1 += __shfl_down(p1, o);
    }
    if (t == 0) {
        out[g * 2 + 0] = p0 + bfc[0];
        out[g * 2 + 1] = p1 + bfc[1];
    }
}

// ---------------- launch ----------------

extern "C" void kernel_launch(void* const* d_in, const int* in_sizes, int n_in,
                              void* d_out, int out_size, void* d_ws, size_t ws_size,
                              hipStream_t stream) {
    const float* x   = (const float*)d_in[0];
    const int*   ei  = (const int*)d_in[1];
    const int*   ngi = (const int*)d_in[2];
    const float* W0  = (const float*)d_in[3];
    const float* b0  = (const float*)d_in[4];
    const float* W1  = (const float*)d_in[5];
    const float* b1  = (const float*)d_in[6];
    const float* Wfc = (const float*)d_in[7];
    const float* bfc = (const float*)d_in[8];
    float* out = (float*)d_out;

    const int* row = ei;
    const int* col = ei + EDGES;

    char* ws = (char*)d_ws;
    size_t o = 0;
    auto alloc = [&](size_t bytes) {
        o = (o + 255) & ~(size_t)255;
        void* p = ws + o;
        o += bytes;
        return p;
    };
    unsigned short* XB  = (unsigned short*)alloc((size_t)NODES * DIN * 2);  // bf16 x
    unsigned short* XA  = (unsigned short*)alloc((size_t)MP * DIN * 2);     // agg(x)
    unsigned short* H   = (unsigned short*)alloc((size_t)MP * HID * 2);     // relu(XA@W0+b0), reused for h2
    unsigned short* G   = (unsigned short*)alloc((size_t)MP * HID * 2);     // H@W1
    unsigned short* W0T = (unsigned short*)alloc((size_t)HID * DIN * 2);
    unsigned short* W1T = (unsigned short*)alloc((size_t)HID * HID * 2);
    float* gh    = (float*)alloc((size_t)GRAPHS * HID * 4);
    int*   deg   = (int*)alloc((size_t)NODES * 4);
    float* dinv  = (float*)alloc((size_t)NODES * 4);
    int*   off   = (int*)alloc((size_t)(NODES + 1) * 4);
    int*   cursor= (int*)alloc((size_t)NODES * 4);
    int*   csr   = (int*)alloc((size_t)EDGES * 4);
    int*   gcnt  = (int*)alloc(512 * 4);
    int*   goff  = (int*)alloc(512 * 4);

    hipMemsetAsync(deg, 0, (size_t)NODES * 4, stream);
    hipMemsetAsync(cursor, 0, (size_t)NODES * 4, stream);
    hipMemsetAsync(gcnt, 0, 512 * 4, stream);
    // pad rows of XA must be finite (GEMM0 reads all MP rows)
    hipMemsetAsync(XA + (size_t)NODES * DIN, 0, (size_t)(MP - NODES) * DIN * 2, stream);

    count_deg<<<(EDGES + 255) / 256, 256, 0, stream>>>(row, deg, EDGES);
    compute_dinv<<<(NODES + 255) / 256, 256, 0, stream>>>(deg, dinv, NODES);
    scan_offsets<<<1, 1024, 0, stream>>>(deg, off, NODES);
    fill_csr<<<(EDGES + 255) / 256, 256, 0, stream>>>(row, col, off, cursor, csr, EDGES);
    count_graph<<<(NODES + 255) / 256, 256, 0, stream>>>(ngi, gcnt, NODES);
    scan_graph<<<1, 512, 0, stream>>>(gcnt, goff);

    cvt_x_bf16<<<((NODES * DIN / 4) + 255) / 256, 256, 0, stream>>>(x, XB, NODES * DIN / 4);
    transpose_w<DIN><<<dim3(2, DIN), 256, 0, stream>>>(W0, W0T);
    transpose_w<HID><<<dim3(2, HID), 256, 0, stream>>>(W1, W1T);

    const int chunks = (NODES + 3) / 4;   // 12500
    // layer 0 (reordered): XA = agg(XB); H = relu(XA @ W0 + b0)
    aggx_g4<<<chunks, 256, 0, stream>>>(XB, off, csr, dinv, XA);
    gemm_mfma<DIN, true><<<4 * (MP / 128), 256, 0, stream>>>(XA, W0T, b0, H);

    // layer 1: G = H @ W1 ; H = relu(agg(G) + b1), 4 feature slices w/ XCD affinity
    gemm_mfma<HID, false><<<4 * (MP / 128), 256, 0, stream>>>(H, W1T, nullptr, G);
    agg512_g4<<<chunks * 4, 256, 0, stream>>>(G, off, csr, dinv, b1, H);

    // pooling + classifier
    pool_bf16<<<GRAPHS, 64, 0, stream>>>(H, goff, gh);
    logits_kernel<<<GRAPHS, 64, 0, stream>>>(gh, Wfc, bfc, out);
}